// Round 15
// baseline (159.095 us; speedup 1.0000x reference)
//
#include <hip/hip_runtime.h>

typedef _Float16 half8 __attribute__((ext_vector_type(8)));
typedef float f32x4 __attribute__((ext_vector_type(4)));
typedef unsigned short u16x8 __attribute__((ext_vector_type(8)));

#define LOG2E 1.44269504088896340736f

constexpr int NB = 16, LQ = 1024, LK = 1024, DX = 512, DVD = 512;
constexpr int QBLK = 32, KVB = 32, NCH = LK / KVB;   // 32 chunks of 32 kv
constexpr int TILE = KVB * DX;                        // 16384 u16 = 32 KB

static __device__ __forceinline__ unsigned short f2h(float f) {
  union { _Float16 h; unsigned short u; } c; c.h = (_Float16)f; return c.u;
}
static __device__ __forceinline__ unsigned int pack2(float a, float b) {
  union { _Float16 h[2]; unsigned int u; } c;
  c.h[0] = (_Float16)a; c.h[1] = (_Float16)b; return c.u;
}
static __device__ __forceinline__ void gload16(const unsigned short* g, unsigned short* l) {
  __builtin_amdgcn_global_load_lds(
      (const __attribute__((address_space(1))) unsigned int*)g,
      (__attribute__((address_space(3))) unsigned int*)l, 16, 0, 0);
}

// ---- prep (r6/r10/r11-verified, KVB=32): f32 -> f16 layout bake.
// K -> Kw[b][c][part=x/8 (64)][kv (32)][8]
// V -> Vw[b][c][pv=kv/8 (4)][d (512)][8]
__global__ __launch_bounds__(256) void prep_kv(
    const float* __restrict__ K, const float* __restrict__ V,
    unsigned short* __restrict__ Kw, unsigned short* __restrict__ Vw) {
  __shared__ float tile[32][520];
  const int bidx = blockIdx.x;
  const bool isV = bidx >= NB * NCH;
  const int bc = isV ? bidx - NB * NCH : bidx;      // b*32 + c
  const int t = (int)threadIdx.x;

  const float* src = (isV ? V : K) + (size_t)bc * (KVB * DX);
#pragma unroll
  for (int i = 0; i < 16; ++i) {
    int idx = t + i * 256;
    int r = idx >> 7, cc = (idx & 127) * 4;
    float4 v = *(const float4*)(src + (size_t)idx * 4);
    *(float4*)&tile[r][cc] = v;
  }
  __syncthreads();

  unsigned short* dst = (isV ? Vw : Kw) + (size_t)bc * TILE;
  if (!isV) {
#pragma unroll
    for (int k = 0; k < 8; ++k) {
      int obi = t * 8 + k;
      int p = obi >> 5, kv = obi & 31;
      const float* rp = &tile[kv][p * 8];
      u16x8 o = { f2h(rp[0]), f2h(rp[1]), f2h(rp[2]), f2h(rp[3]),
                  f2h(rp[4]), f2h(rp[5]), f2h(rp[6]), f2h(rp[7]) };
      *(u16x8*)(dst + obi * 8) = o;
    }
  } else {
#pragma unroll
    for (int k = 0; k < 8; ++k) {
      int vbi = t * 8 + k;
      int pv = vbi >> 9, d = vbi & 511;
      u16x8 o = { f2h(tile[pv * 8 + 0][d]), f2h(tile[pv * 8 + 1][d]),
                  f2h(tile[pv * 8 + 2][d]), f2h(tile[pv * 8 + 3][d]),
                  f2h(tile[pv * 8 + 4][d]), f2h(tile[pv * 8 + 5][d]),
                  f2h(tile[pv * 8 + 6][d]), f2h(tile[pv * 8 + 7][d]) };
      *(u16x8*)(dst + vbi * 8) = o;
    }
  }
}

// ---- main: 384-thr blocks (2 QK + 4 PV waves), QBLK=32, grid 512 ->
// 2 blocks/CU (LDS ~69 KB, VGPR cap ~170). Single-buffered K/V; the DMA
// wait at barrier B is hidden by the co-resident block's compute.
__global__ __launch_bounds__(384) void attn_db(
    const float* __restrict__ Qf, const unsigned short* __restrict__ Kw,
    const unsigned short* __restrict__ Vw, float* __restrict__ Out) {
  __shared__ __align__(16) unsigned short Kl[TILE];      // 32 KB, holds K(p)
  __shared__ __align__(16) unsigned short Vl[TILE];      // 32 KB, holds V(p-1)
  __shared__ __align__(16) unsigned short Pl[2][1024];   // [buf][pp 4][q 32][8]
  __shared__ __align__(16) float sml[2][32];
  __shared__ __align__(16) float lfin[32];
  __shared__ __align__(16) int rflag[2][2];

  const int bid = blockIdx.x;
  const int logical = (bid & 7) * 64 + (bid >> 3);  // XCD-chunked: 2 batches/XCD
  const int b  = logical >> 5;
  const int qt = logical & 31;
  const int tid = (int)threadIdx.x;
  const int lane = tid & 63;
  const int wave = tid >> 6;            // 0..5
  const bool isQK = wave < 2;
  const int qs = wave;                  // QK q-sub (16 q)
  const int wd = wave - 2;              // PV d-slice (128 d)
  const int c15 = lane & 15;
  const int g4  = lane >> 4;
  const int rbase = g4 * 4;
  const int d0 = wd * 128;

  // blk: QK waves = qfrag (bitcast half8); PV waves = acc[2][8] (s*8+n).
  f32x4 blk[16];
  float mr = -3.0e38f, lr = 0.f;

  if (isQK) {
    const float* qrow = Qf + ((size_t)b * LQ + qt * QBLK + qs * 16 + c15) * DX + g4 * 8;
#pragma unroll
    for (int ks = 0; ks < 16; ++ks) {
      float4 a0 = *(const float4*)(qrow + ks * 32);
      float4 a1 = *(const float4*)(qrow + ks * 32 + 4);
      half8 f;
      f[0] = (_Float16)(a0.x * LOG2E); f[1] = (_Float16)(a0.y * LOG2E);
      f[2] = (_Float16)(a0.z * LOG2E); f[3] = (_Float16)(a0.w * LOG2E);
      f[4] = (_Float16)(a1.x * LOG2E); f[5] = (_Float16)(a1.y * LOG2E);
      f[6] = (_Float16)(a1.z * LOG2E); f[7] = (_Float16)(a1.w * LOG2E);
      blk[ks] = __builtin_bit_cast(f32x4, f);
    }
  } else {
#pragma unroll
    for (int i = 0; i < 16; ++i) blk[i] = (f32x4){0.f, 0.f, 0.f, 0.f};
  }

  // staging owned by PV threads (tid 128..383 -> st 0..255, 8 insts/tile)
  const int st = tid - 128;
  const unsigned short* kg = Kw + (size_t)b * NCH * TILE + st * 8;
  const unsigned short* vg = Vw + (size_t)b * NCH * TILE + st * 8;

  if (!isQK) {
#pragma unroll
    for (int ii = 0; ii < 8; ++ii) gload16(kg + ii * 2048, &Kl[st * 8 + ii * 2048]);
  }
  asm volatile("s_waitcnt vmcnt(0)" ::: "memory");
  __syncthreads();

  for (int ph = 0; ph <= NCH; ++ph) {
    const int cb = ph & 1, pb = cb ^ 1;

    if (isQK) {
      if (ph < NCH) {
        // ---- QK^T chunk ph on Kl (swapped: lane owns q=c15, kv=g4*4+j(+16))
        f32x4 cs0 = {0.f, 0.f, 0.f, 0.f};
        f32x4 cs1 = {0.f, 0.f, 0.f, 0.f};
        {
          const unsigned short* kb = &Kl[c15 * 8 + g4 * 256];
          __builtin_amdgcn_s_setprio(1);
#pragma unroll
          for (int ks = 0; ks < 16; ++ks) {
            const unsigned short* kp = kb + ks * 1024;   // part = ks*4+g4
            half8 a0 = *(const half8*)kp;                // kv = c15
            half8 a1 = *(const half8*)(kp + 128);        // kv = 16+c15
            half8 qv = __builtin_bit_cast(half8, blk[ks]);
            cs0 = __builtin_amdgcn_mfma_f32_16x16x32_f16(a0, qv, cs0, 0, 0, 0);
            cs1 = __builtin_amdgcn_mfma_f32_16x16x32_f16(a1, qv, cs1, 0, 0, 0);
          }
          __builtin_amdgcn_s_setprio(0);
        }

        // ---- in-wave online softmax, defer-max THR=8 (log2 units)
        float pm = fmaxf(fmaxf(fmaxf(cs0[0], cs0[1]), fmaxf(cs0[2], cs0[3])),
                         fmaxf(fmaxf(cs1[0], cs1[1]), fmaxf(cs1[2], cs1[3])));
        pm = fmaxf(pm, __shfl_xor(pm, 16, 64));
        pm = fmaxf(pm, __shfl_xor(pm, 32, 64));
        const bool resc = __any(pm > mr + 8.0f);
        float scl = 1.0f;
        if (resc) {
          float mn = fmaxf(mr, pm);
          scl = exp2f(mr - mn);
          mr = mn;
        }
        if (g4 == 0) sml[cb][qs * 16 + c15] = scl;
        if (lane == 0) rflag[cb][qs] = resc ? 1 : 0;
        float p0[4], p1[4];
#pragma unroll
        for (int j = 0; j < 4; ++j) {
          p0[j] = exp2f(cs0[j] - mr);
          p1[j] = exp2f(cs1[j] - mr);
        }
        float ps = ((p0[0] + p0[1]) + (p0[2] + p0[3]))
                 + ((p1[0] + p1[1]) + (p1[2] + p1[3]));
        ps += __shfl_xor(ps, 16, 64);
        ps += __shfl_xor(ps, 32, 64);
        lr = lr * scl + ps;

        // ---- P write: q=qs*16+c15, kv = g4*4+j (+16); pp stride 256
        {
          unsigned short* pw = &Pl[cb][(g4 >> 1) * 256 + (qs * 16 + c15) * 8 + (g4 & 1) * 4];
          uint2 w0 = { pack2(p0[0], p0[1]), pack2(p0[2], p0[3]) };
          uint2 w1 = { pack2(p1[0], p1[1]), pack2(p1[2], p1[3]) };
          *(uint2*)pw         = w0;    // pp = (g4>>1)
          *(uint2*)(pw + 512) = w1;    // pp = 2 + (g4>>1)
        }
        if (ph == NCH - 1 && g4 == 0) lfin[qs * 16 + c15] = lr;
      }
    } else {
      if (ph > 0) {
        // ---- PV chunk ph-1: O[32q x 128d] from Pl[pb] + Vl (V(ph-1))
        half8 pa0 = *(const half8*)&Pl[pb][g4 * 256 + c15 * 8];         // q-sub 0
        half8 pa1 = *(const half8*)&Pl[pb][g4 * 256 + (16 + c15) * 8];  // q-sub 1
        half8 bv[8];
#pragma unroll
        for (int n = 0; n < 8; ++n)
          bv[n] = *(const half8*)&Vl[g4 * 4096 + (d0 + n * 16 + c15) * 8];
        const int fl = rflag[pb][0] | rflag[pb][1];
        if (fl) {
          f32x4 sv0 = *(const f32x4*)&sml[pb][rbase];
          f32x4 sv1 = *(const f32x4*)&sml[pb][16 + rbase];
#pragma unroll
          for (int n = 0; n < 8; ++n)
#pragma unroll
            for (int j = 0; j < 4; ++j) {
              blk[n][j]     *= sv0[j];
              blk[8 + n][j] *= sv1[j];
            }
        }
        __builtin_amdgcn_s_setprio(1);
#pragma unroll
        for (int n = 0; n < 8; ++n) {
          blk[n]     = __builtin_amdgcn_mfma_f32_16x16x32_f16(pa0, bv[n], blk[n], 0, 0, 0);
          blk[8 + n] = __builtin_amdgcn_mfma_f32_16x16x32_f16(pa1, bv[n], blk[8 + n], 0, 0, 0);
        }
        __builtin_amdgcn_s_setprio(0);
      }
    }

    // ---- barrier A: all LDS reads of Kl/Vl returned; P/sml/rflag published
    asm volatile("s_waitcnt lgkmcnt(0)" ::: "memory");
    __builtin_amdgcn_s_barrier();
    __builtin_amdgcn_sched_barrier(0);

    // ---- DMA slot (PV threads): K(ph+1) -> Kl, V(ph) -> Vl
    if (!isQK) {
      if (ph + 1 < NCH) {
        const unsigned short* ks_ = kg + (size_t)(ph + 1) * TILE;
#pragma unroll
        for (int ii = 0; ii < 8; ++ii) gload16(ks_ + ii * 2048, &Kl[st * 8 + ii * 2048]);
      }
      if (ph < NCH) {
        const unsigned short* vs_ = vg + (size_t)ph * TILE;
#pragma unroll
        for (int ii = 0; ii < 8; ++ii) gload16(vs_ + ii * 2048, &Vl[st * 8 + ii * 2048]);
      }
    }

    // ---- barrier B: DMA landed (vmcnt 0; trivially 0 for QK waves).
    //      Stall here is filled by the co-resident block's compute.
    asm volatile("s_waitcnt vmcnt(0) lgkmcnt(0)" ::: "memory");
    __builtin_amdgcn_s_barrier();
    __builtin_amdgcn_sched_barrier(0);
  }

  // ---- epilogue (PV waves hold O): O /= l, store f32
  if (!isQK) {
#pragma unroll
    for (int s = 0; s < 2; ++s) {
      f32x4 lv = *(const f32x4*)&lfin[s * 16 + rbase];
      float inv[4];
#pragma unroll
      for (int j = 0; j < 4; ++j) inv[j] = 1.0f / lv[j];
      float* ob = Out + ((size_t)b * LQ + qt * QBLK + s * 16 + rbase) * DVD + d0 + c15;
#pragma unroll
      for (int n = 0; n < 8; ++n)
#pragma unroll
        for (int j = 0; j < 4; ++j)
          ob[(size_t)j * DVD + n * 16] = blk[s * 8 + n][j] * inv[j];
    }
  }
}

extern "C" void kernel_launch(void* const* d_in, const int* in_sizes, int n_in,
                              void* d_out, int out_size, void* d_ws, size_t ws_size,
                              hipStream_t stream) {
  const float* Qf = (const float*)d_in[0];
  const float* Kf = (const float*)d_in[1];
  const float* Vf = (const float*)d_in[2];
  float* Out = (float*)d_out;

  unsigned short* Kw = (unsigned short*)d_ws;
  unsigned short* Vw = Kw + (size_t)NB * NCH * TILE;   // 16.7 MB each

  prep_kv<<<NB * NCH * 2, 256, 0, stream>>>(Kf, Vf, Kw, Vw);
  attn_db<<<NB * (LQ / QBLK), 384, 0, stream>>>(Qf, Kw, Vw, Out);
}

// Round 16
// 79.808 us; speedup vs baseline: 1.9935x; 1.9935x over previous
//
#include <hip/hip_runtime.h>

typedef _Float16 half8 __attribute__((ext_vector_type(8)));
typedef float f32x4 __attribute__((ext_vector_type(4)));
typedef unsigned short u16x8 __attribute__((ext_vector_type(8)));

#define LOG2E 1.44269504088896340736f

constexpr int NB = 16, LQ = 1024, LK = 1024, DX = 512, DVD = 512;
constexpr int QBLK = 64, KVB = 32, NCH = LK / KVB;   // 32 chunks of 32 kv
constexpr int TILE = KVB * DX;                        // 16384 u16 = 32 KB

static __device__ __forceinline__ unsigned short f2h(float f) {
  union { _Float16 h; unsigned short u; } c; c.h = (_Float16)f; return c.u;
}
static __device__ __forceinline__ unsigned int pack2(float a, float b) {
  union { _Float16 h[2]; unsigned int u; } c;
  c.h[0] = (_Float16)a; c.h[1] = (_Float16)b; return c.u;
}
static __device__ __forceinline__ void gload16(const unsigned short* g, unsigned short* l) {
  __builtin_amdgcn_global_load_lds(
      (const __attribute__((address_space(1))) unsigned int*)g,
      (__attribute__((address_space(3))) unsigned int*)l, 16, 0, 0);
}

// ---- prep: f32 -> f16 with layout bake into 32-KB (b,c) tiles (r6-verified).
// K -> Kw[b][c][part=x/8 (64)][kv (32)][8]
// V -> Vw[b][c][pv=kv/8 (4)][d (512)][8]
__global__ __launch_bounds__(256) void prep_kv(
    const float* __restrict__ K, const float* __restrict__ V,
    unsigned short* __restrict__ Kw, unsigned short* __restrict__ Vw) {
  __shared__ float tile[32][520];
  const int bidx = blockIdx.x;
  const bool isV = bidx >= NB * NCH;
  const int bc = isV ? bidx - NB * NCH : bidx;      // b*32 + c
  const int t = (int)threadIdx.x;

  const float* src = (isV ? V : K) + (size_t)bc * (KVB * DX);
#pragma unroll
  for (int i = 0; i < 16; ++i) {
    int idx = t + i * 256;
    int r = idx >> 7, cc = (idx & 127) * 4;
    float4 v = *(const float4*)(src + (size_t)idx * 4);
    *(float4*)&tile[r][cc] = v;
  }
  __syncthreads();

  unsigned short* dst = (isV ? Vw : Kw) + (size_t)bc * TILE;
  if (!isV) {
#pragma unroll
    for (int k = 0; k < 8; ++k) {
      int obi = t * 8 + k;
      int p = obi >> 5, kv = obi & 31;
      const float* rp = &tile[kv][p * 8];
      u16x8 o = { f2h(rp[0]), f2h(rp[1]), f2h(rp[2]), f2h(rp[3]),
                  f2h(rp[4]), f2h(rp[5]), f2h(rp[6]), f2h(rp[7]) };
      *(u16x8*)(dst + obi * 8) = o;
    }
  } else {
#pragma unroll
    for (int k = 0; k < 8; ++k) {
      int vbi = t * 8 + k;
      int pv = vbi >> 9, d = vbi & 511;
      u16x8 o = { f2h(tile[pv * 8 + 0][d]), f2h(tile[pv * 8 + 1][d]),
                  f2h(tile[pv * 8 + 2][d]), f2h(tile[pv * 8 + 3][d]),
                  f2h(tile[pv * 8 + 4][d]), f2h(tile[pv * 8 + 5][d]),
                  f2h(tile[pv * 8 + 6][d]), f2h(tile[pv * 8 + 7][d]) };
      *(u16x8*)(dst + vbi * 8) = o;
    }
  }
}

// ---- main: wave-specialized producer/consumer, 1 barrier per chunk.
// 12 waves: 0..3 = QK role (16 q each, full 32-kv chunk, in-wave softmax);
//           4..11 = PV role (64 q x 64 d each) consuming chunk c-1 + all DMA.
// Measured best (r11): attn 68.4 us, VGPR 80, zero spill. r12-r15 neighbors
// (KVB=64, V-direct, 2-blk/CU, launch-bounds variants) all measured worse.
__global__ __launch_bounds__(768) void attn_ws(
    const float* __restrict__ Qf, const unsigned short* __restrict__ Kw,
    const unsigned short* __restrict__ Vw, float* __restrict__ Out) {
  __shared__ __align__(16) unsigned short Kl[2][TILE];   // 64 KB
  __shared__ __align__(16) unsigned short Vl[2][TILE];   // 64 KB
  __shared__ __align__(16) unsigned short Pl[2][2048];   // [buf][pp 4][q 64][8] 8 KB
  __shared__ __align__(16) float sml[2][64];
  __shared__ __align__(16) float lfin[64];
  __shared__ __align__(16) int rflag[2][4];

  const int bid = blockIdx.x;
  const int logical = (bid & 7) * 32 + (bid >> 3);  // XCD-chunked: 2 batches/XCD
  const int b  = logical >> 4;
  const int qt = logical & 15;
  const int tid = (int)threadIdx.x;
  const int lane = tid & 63;
  const int wave = tid >> 6;            // 0..11
  const bool isQK = wave < 4;
  const int qs = wave;                  // QK q-sub (16 q), valid when isQK
  const int wd = wave - 4;              // PV d-slice (64 d), valid when !isQK
  const int c15 = lane & 15;
  const int g4  = lane >> 4;
  const int rbase = g4 * 4;

  // blk: QK waves use as qfrag (bitcast half8); PV waves use as acc[4][4].
  f32x4 blk[16];
  float mr = -3.0e38f, lr = 0.f;

  if (isQK) {
    const float* qrow = Qf + ((size_t)b * LQ + qt * QBLK + qs * 16 + c15) * DX + g4 * 8;
#pragma unroll
    for (int ks = 0; ks < 16; ++ks) {
      float4 a0 = *(const float4*)(qrow + ks * 32);
      float4 a1 = *(const float4*)(qrow + ks * 32 + 4);
      half8 f;
      f[0] = (_Float16)(a0.x * LOG2E); f[1] = (_Float16)(a0.y * LOG2E);
      f[2] = (_Float16)(a0.z * LOG2E); f[3] = (_Float16)(a0.w * LOG2E);
      f[4] = (_Float16)(a1.x * LOG2E); f[5] = (_Float16)(a1.y * LOG2E);
      f[6] = (_Float16)(a1.z * LOG2E); f[7] = (_Float16)(a1.w * LOG2E);
      blk[ks] = __builtin_bit_cast(f32x4, f);
    }
  } else {
#pragma unroll
    for (int i = 0; i < 16; ++i) blk[i] = (f32x4){0.f, 0.f, 0.f, 0.f};
  }

  // staging owned by PV waves (tid >= 256 -> 512 threads)
  const int st = tid - 256;             // 0..511 for staging threads
  const unsigned short* kg = Kw + (size_t)b * NCH * TILE + st * 8;
  const unsigned short* vg = Vw + (size_t)b * NCH * TILE + st * 8;

  // prologue: stage K(0) into Kl[0]
  if (tid >= 256) {
#pragma unroll
    for (int ii = 0; ii < 4; ++ii) gload16(kg + ii * 4096, &Kl[0][st * 8 + ii * 4096]);
  }
  __syncthreads();

  for (int p = 0; p <= NCH; ++p) {
    const int cb = p & 1, pbuf = cb ^ 1;

    // ---- staging at phase top (PV waves): K(p+1) -> Kl[pbuf], V(p) -> Vl[cb]
    if (tid >= 256) {
      if (p + 1 < NCH) {
        const unsigned short* ks_ = kg + (size_t)(p + 1) * TILE;
#pragma unroll
        for (int ii = 0; ii < 4; ++ii)
          gload16(ks_ + ii * 4096, &Kl[pbuf][st * 8 + ii * 4096]);
      }
      if (p < NCH) {
        const unsigned short* vs_ = vg + (size_t)p * TILE;
#pragma unroll
        for (int ii = 0; ii < 4; ++ii)
          gload16(vs_ + ii * 4096, &Vl[cb][st * 8 + ii * 4096]);
      }
    }

    if (isQK) {
      if (p < NCH) {
        // ---- QK^T chunk p: swapped mfma(K,Q); lane owns q=c15, 8 kv values
        f32x4 cs0 = {0.f, 0.f, 0.f, 0.f};
        f32x4 cs1 = {0.f, 0.f, 0.f, 0.f};
        __builtin_amdgcn_s_setprio(1);
#pragma unroll
        for (int ks = 0; ks < 16; ++ks) {
          const int po = (ks * 4 + g4) * 256;
          half8 a0 = *(const half8*)&Kl[cb][c15 * 8 + po];          // kv=c15
          half8 a1 = *(const half8*)&Kl[cb][(16 + c15) * 8 + po];   // kv=16+c15
          half8 qv = __builtin_bit_cast(half8, blk[ks]);
          cs0 = __builtin_amdgcn_mfma_f32_16x16x32_f16(a0, qv, cs0, 0, 0, 0);
          cs1 = __builtin_amdgcn_mfma_f32_16x16x32_f16(a1, qv, cs1, 0, 0, 0);
        }
        __builtin_amdgcn_s_setprio(0);

        // ---- fully in-wave online softmax (q-row = c15), defer-max THR=8
        float pm = fmaxf(fmaxf(fmaxf(cs0[0], cs0[1]), fmaxf(cs0[2], cs0[3])),
                         fmaxf(fmaxf(cs1[0], cs1[1]), fmaxf(cs1[2], cs1[3])));
        pm = fmaxf(pm, __shfl_xor(pm, 16, 64));
        pm = fmaxf(pm, __shfl_xor(pm, 32, 64));
        const bool resc = __any(pm > mr + 8.0f);
        float scl = 1.0f;
        if (resc) {
          float mn = fmaxf(mr, pm);
          scl = exp2f(mr - mn);
          mr = mn;
        }
        if (g4 == 0) sml[cb][qs * 16 + c15] = scl;
        if (lane == 0) rflag[cb][qs] = resc ? 1 : 0;
        float p0[4], p1[4];
#pragma unroll
        for (int j = 0; j < 4; ++j) {
          p0[j] = exp2f(cs0[j] - mr);
          p1[j] = exp2f(cs1[j] - mr);
        }
        float ps = ((p0[0] + p0[1]) + (p0[2] + p0[3]))
                 + ((p1[0] + p1[1]) + (p1[2] + p1[3]));
        ps += __shfl_xor(ps, 16, 64);
        ps += __shfl_xor(ps, 32, 64);
        lr = lr * scl + ps;

        // ---- P write: q=qs*16+c15; kv = kvs*16 + g4*4 + j  (r7-verified map)
        {
          unsigned short* pw = &Pl[cb][(g4 >> 1) * 512 + (qs * 16 + c15) * 8 + (g4 & 1) * 4];
          uint2 w0 = { pack2(p0[0], p0[1]), pack2(p0[2], p0[3]) };
          uint2 w1 = { pack2(p1[0], p1[1]), pack2(p1[2], p1[3]) };
          *(uint2*)pw          = w0;     // pp = (g4>>1)       (kvs=0)
          *(uint2*)(pw + 1024) = w1;     // pp = 2 + (g4>>1)   (kvs=1)
        }
        if (p == NCH - 1 && g4 == 0) lfin[qs * 16 + c15] = lr;
      }
    } else {
      if (p > 0) {
        // ---- PV chunk p-1: O[64q x 64d], A=P from Pl[pbuf], B=V from Vl[pbuf]
        int4 f4 = *(const int4*)&rflag[pbuf][0];
        const int fl = f4.x | f4.y | f4.z | f4.w;
        half8 pa0 = *(const half8*)&Pl[pbuf][g4 * 512 + (c15) * 8];
        half8 pa1 = *(const half8*)&Pl[pbuf][g4 * 512 + (16 + c15) * 8];
        half8 pa2 = *(const half8*)&Pl[pbuf][g4 * 512 + (32 + c15) * 8];
        half8 pa3 = *(const half8*)&Pl[pbuf][g4 * 512 + (48 + c15) * 8];
        half8 bv0 = *(const half8*)&Vl[pbuf][g4 * 4096 + (wd * 64 + c15) * 8];
        half8 bv1 = *(const half8*)&Vl[pbuf][g4 * 4096 + (wd * 64 + 16 + c15) * 8];
        half8 bv2 = *(const half8*)&Vl[pbuf][g4 * 4096 + (wd * 64 + 32 + c15) * 8];
        half8 bv3 = *(const half8*)&Vl[pbuf][g4 * 4096 + (wd * 64 + 48 + c15) * 8];
        if (fl) {
#pragma unroll
          for (int s = 0; s < 4; ++s) {
            f32x4 sv = *(const f32x4*)&sml[pbuf][s * 16 + rbase];
#pragma unroll
            for (int n = 0; n < 4; ++n)
#pragma unroll
              for (int j = 0; j < 4; ++j) blk[s * 4 + n][j] *= sv[j];
          }
        }
        __builtin_amdgcn_s_setprio(1);
#pragma unroll
        for (int s = 0; s < 4; ++s) {
          half8 pas = (s == 0) ? pa0 : (s == 1) ? pa1 : (s == 2) ? pa2 : pa3;
          blk[s * 4 + 0] = __builtin_amdgcn_mfma_f32_16x16x32_f16(pas, bv0, blk[s * 4 + 0], 0, 0, 0);
          blk[s * 4 + 1] = __builtin_amdgcn_mfma_f32_16x16x32_f16(pas, bv1, blk[s * 4 + 1], 0, 0, 0);
          blk[s * 4 + 2] = __builtin_amdgcn_mfma_f32_16x16x32_f16(pas, bv2, blk[s * 4 + 2], 0, 0, 0);
          blk[s * 4 + 3] = __builtin_amdgcn_mfma_f32_16x16x32_f16(pas, bv3, blk[s * 4 + 3], 0, 0, 0);
        }
        __builtin_amdgcn_s_setprio(0);
      }
    }

    // ---- single per-phase barrier: drains this phase's DMA (consumed next
    //      phase) + publishes P/sml/rflag/lfin LDS writes.
    asm volatile("s_waitcnt vmcnt(0) lgkmcnt(0)" ::: "memory");
    __builtin_amdgcn_s_barrier();
    __builtin_amdgcn_sched_barrier(0);
  }

  // ---- epilogue (PV waves hold O): O /= l, store f32
  if (!isQK) {
#pragma unroll
    for (int s = 0; s < 4; ++s) {
      f32x4 lv = *(const f32x4*)&lfin[s * 16 + rbase];
      float inv[4];
#pragma unroll
      for (int j = 0; j < 4; ++j) inv[j] = 1.0f / lv[j];
      float* ob = Out + ((size_t)b * LQ + qt * QBLK + s * 16 + rbase) * DVD
                  + wd * 64 + c15;
#pragma unroll
      for (int n = 0; n < 4; ++n)
#pragma unroll
        for (int j = 0; j < 4; ++j)
          ob[(size_t)j * DVD + n * 16] = blk[s * 4 + n][j] * inv[j];
    }
  }
}

extern "C" void kernel_launch(void* const* d_in, const int* in_sizes, int n_in,
                              void* d_out, int out_size, void* d_ws, size_t ws_size,
                              hipStream_t stream) {
  const float* Qf = (const float*)d_in[0];
  const float* Kf = (const float*)d_in[1];
  const float* Vf = (const float*)d_in[2];
  float* Out = (float*)d_out;

  unsigned short* Kw = (unsigned short*)d_ws;
  unsigned short* Vw = Kw + (size_t)NB * NCH * TILE;   // 16.7 MB each

  prep_kv<<<NB * NCH * 2, 256, 0, stream>>>(Kf, Vf, Kw, Vw);
  attn_ws<<<NB * (LQ / QBLK), 768, 0, stream>>>(Qf, Kw, Vw, Out);
}